// Round 7
// baseline (26.142 us; speedup 1.0000x reference)
//
#include <hip/hip_runtime.h>

// JPEG differentiable codec, fused. Identity: IDCT(DCT(p)+nf) = p + IDCT(nf);
// only the quantization NOISE is IDCT'd: nf = 0.125*eps*table*AA*rv.
// Round-6: round-5's barrier-free wave-autonomous structure (validated,
// absmax 1.0), but each wave processes TWO adjacent 16x16 tiles with ALL
// global loads (both tiles) issued before any compute -> tile-1's 5 loads
// stay in flight through tile-0's entire compute phase, ~2x per-wave
// outstanding bytes in the previously-dry window (latency-bound theory).
// LDS slice reused across the two tiles: wave-internal in-order DS ops make
// the write-after-read safe without any barrier.
//
// Index map (validated rounds 0-5): img[b,i,j,c] = pixel_inp[b,c,j,i];
// Y block n = (i/8)*32 + j/8, in-block offset = (i%8)*8 + (j%8); ref tables
// are .T so table[x][y] = std[y][x]; chroma at (ci,cj)=(i/2,j/2),
// n_c = (ci/8)*16 + cj/8.
//
// Per-wave LDS slice (words): sY@0 [q:4][v:8 s12][x:8]=416 (scalar writes
// conflict-free); sC@416 [ch:2][v:8 s12][x:8]=208; ny@624 [j:16 s20][i:16]
// =320; pool@944 [ch:2 s96][cj:8 s12][ci:8]=192; total 1136 w = 4.44 KB.

__constant__ float YBT[64] = {   // YBT[x*8+y] = std_luma[y][x]
  16,12,14,14,18,24,49,72,
  11,12,13,17,22,35,64,92,
  10,14,16,22,37,55,78,95,
  16,19,24,29,56,64,87,98,
  24,26,40,51,68,81,103,112,
  40,58,57,87,109,104,121,100,
  51,60,69,80,103,113,120,103,
  61,55,56,62,77,92,101,99};

__constant__ float CBTc[64] = {  // symmetric -> transpose = itself
  17,18,24,47,99,99,99,99,
  18,21,26,66,99,99,99,99,
  24,26,56,99,99,99,99,99,
  47,66,99,99,99,99,99,99,
  99,99,99,99,99,99,99,99,
  99,99,99,99,99,99,99,99,
  99,99,99,99,99,99,99,99,
  99,99,99,99,99,99,99,99};

typedef float f4v __attribute__((ext_vector_type(4)));
typedef float f2v __attribute__((ext_vector_type(2)));

// o[u] = sum_k t[k] * cos((2u+1)*k*pi/16)
__device__ __forceinline__ void idct8(const float* __restrict__ t,
                                      float* __restrict__ o) {
    const float r  = 0.70710678118654752f;
    const float a  = 0.92387953251128674f;
    const float bq = 0.38268343236508977f;
    const float c1 = 0.98078528040323044f;
    const float c3 = 0.83146961230254524f;
    const float c5 = 0.55557023301960222f;
    const float c7 = 0.19509032201612827f;
    const float p  = fmaf(r,  t[4], t[0]);
    const float m  = fmaf(-r, t[4], t[0]);
    const float q  = fmaf(a,  t[2],  bq*t[6]);
    const float s  = fmaf(bq, t[2],  -a*t[6]);
    const float E0 = p + q, E3 = p - q, E1 = m + s, E2 = m - s;
    const float O0 = fmaf(c1,t[1], fmaf( c3,t[3], fmaf( c5,t[5],  c7*t[7])));
    const float O1 = fmaf(c3,t[1], fmaf(-c7,t[3], fmaf(-c1,t[5], -c5*t[7])));
    const float O2 = fmaf(c5,t[1], fmaf(-c1,t[3], fmaf( c7,t[5],  c3*t[7])));
    const float O3 = fmaf(c7,t[1], fmaf(-c5,t[3], fmaf( c3,t[5], -c1*t[7])));
    o[0]=E0+O0; o[7]=E0-O0; o[1]=E1+O1; o[6]=E1-O1;
    o[2]=E2+O2; o[5]=E2-O2; o[3]=E3+O3; o[4]=E3-O3;
}

__device__ __forceinline__ void process_tile(
    float* __restrict__ wlds, float* __restrict__ out, size_t pb, int lane,
    float aax,
    const float4 v0, const float4 v1, const float4 t0, const float4 t1,
    const float4 rP, const float4 gP, const float4 bP)
{
    const float RT = 0.70710678118654752f;
    const int  xc   = lane & 7;
    const int  q1   = (lane >> 3) & 3;
    const int  cq   = (lane >> 3) & 1;
    const bool isY1 = lane < 32;
    const int  pi   = (lane & 3)*4;
    const int  pj   = lane >> 2;

    // ---- stage 1: column IDCT of scaled noise ----
    {
        float t[8], o[8];
        t[0] = v0.x * (t0.x * aax * RT);   // alpha_y on y=0
        t[1] = v0.y * (t0.y * aax);
        t[2] = v0.z * (t0.z * aax);
        t[3] = v0.w * (t0.w * aax);
        t[4] = v1.x * (t1.x * aax);
        t[5] = v1.y * (t1.y * aax);
        t[6] = v1.z * (t1.z * aax);
        t[7] = v1.w * (t1.w * aax);
        idct8(t, o);
        if (lane < 48) {
            float* w = wlds + (isY1 ? q1*104 : 416 + cq*104) + xc;
            #pragma unroll
            for (int v = 0; v < 8; ++v) w[v*12] = o[v];
        }
    }

    // ---- YCC + chroma 2x2 pool (intra-wave shuffles) ----
    const float rr[4] = {rP.x, rP.y, rP.z, rP.w};
    const float gg[4] = {gP.x, gP.y, gP.z, gP.w};
    const float bb[4] = {bP.x, bP.y, bP.z, bP.w};
    float yv[4], cbv[4], crv[4];
    #pragma unroll
    for (int c = 0; c < 4; ++c) {
        yv[c]  = fmaf(0.299f, rr[c], fmaf(0.587f, gg[c], 0.114f*bb[c]));
        cbv[c] = fmaf(-0.168736f, rr[c], fmaf(-0.331264f, gg[c], 0.5f*bb[c]));
        crv[c] = fmaf(0.5f, rr[c], fmaf(-0.418688f, gg[c], -0.081312f*bb[c]));
    }
    float cb01 = cbv[0] + cbv[1], cb23 = cbv[2] + cbv[3];
    float cr01 = crv[0] + crv[1], cr23 = crv[2] + crv[3];
    cb01 += __shfl_xor(cb01, 4);   // partner row pj^1 (pj bit0 = lane bit2)
    cb23 += __shfl_xor(cb23, 4);
    cr01 += __shfl_xor(cr01, 4);
    cr23 += __shfl_xor(cr23, 4);
    if (!(lane & 4)) {             // even pj: centered pooled chroma (no +128)
        const int cj = pj >> 1, ci = pi >> 1;
        *(f2v*)(wlds + 944  + cj*12 + ci) = (f2v){0.25f*cb01, 0.25f*cb23};
        *(f2v*)(wlds + 1040 + cj*12 + ci) = (f2v){0.25f*cr01, 0.25f*cr23};
    }

    // ---- stage 2: row IDCT (wave-internal LDS RAW, no barrier) ----
    {
        const int v2 = lane & 7;
        const float* rs = wlds + (isY1 ? q1*104 : 416 + cq*104) + v2*12;
        const f4v lo = *(const f4v*)rs;
        const f4v hi = *(const f4v*)(rs + 4);
        float t[8] = {lo.x, lo.y, lo.z, lo.w, hi.x, hi.y, hi.z, hi.w};
        float o[8];
        idct8(t, o);
        if (isY1) {                // Y noise -> ny[j][i]
            float* w = wlds + 624 + ((q1 & 1)*8 + v2)*20 + (q1 >> 1)*8;
            *(f4v*)w       = (f4v){o[0], o[1], o[2], o[3]};
            *(f4v*)(w + 4) = (f4v){o[4], o[5], o[6], o[7]};
        } else if (lane < 48) {    // chroma noise: add into pool row cj=v2
            float* pp = wlds + 944 + cq*96 + v2*12;
            f4v p0 = *(f4v*)pp, p1 = *(f4v*)(pp + 4);
            p0 += (f4v){o[0], o[1], o[2], o[3]};
            p1 += (f4v){o[4], o[5], o[6], o[7]};
            *(f4v*)pp       = p0;
            *(f4v*)(pp + 4) = p1;
        }
    }

    // ---- final: recombine, YCC->RGB, clip, store ----
    const f4v yn4 = *(const f4v*)(wlds + 624 + pj*20 + pi);
    const int cjf = pj >> 1, cif = pi >> 1;
    const f2v cbp = *(const f2v*)(wlds + 944  + cjf*12 + cif);
    const f2v crp = *(const f2v*)(wlds + 1040 + cjf*12 + cif);
    const float yn[4]  = {yn4.x, yn4.y, yn4.z, yn4.w};
    const float cbf[4] = {cbp.x, cbp.x, cbp.y, cbp.y};
    const float crf[4] = {crp.x, crp.x, crp.y, crp.y};
    float ro[4], go[4], bo[4];
    #pragma unroll
    for (int c = 0; c < 4; ++c) {
        const float yf = yv[c] + yn[c];
        float r_ = fmaf(1.402f, crf[c], yf);
        float g_ = fmaf(-0.344136f, cbf[c], fmaf(-0.714136f, crf[c], yf));
        float b_ = fmaf(1.772f, cbf[c], yf);
        ro[c] = fminf(fmaxf(r_, 0.0f), 255.0f);
        go[c] = fminf(fmaxf(g_, 0.0f), 255.0f);
        bo[c] = fminf(fmaxf(b_, 0.0f), 255.0f);
    }
    *(float4*)(out + pb)          = make_float4(ro[0], ro[1], ro[2], ro[3]);
    *(float4*)(out + pb + 65536)  = make_float4(go[0], go[1], go[2], go[3]);
    *(float4*)(out + pb + 131072) = make_float4(bo[0], bo[1], bo[2], bo[3]);
}

__global__ __launch_bounds__(256, 5) void jpeg_kernel(
    const float* __restrict__ pix,   // [B,3,256,256]
    const float* __restrict__ rvy,   // [B,1024,8,8]
    const float* __restrict__ rvcb,  // [B,256,8,8]
    const float* __restrict__ rvcr,  // [B,256,8,8]
    const float* __restrict__ epsv,  // [B]
    float* __restrict__ out)         // [B,3,256,256]
{
    __shared__ __align__(16) float lds[4*1136];

    const int tid  = threadIdx.x;
    const int lane = tid & 63;
    const int wv   = tid >> 6;
    const int b    = blockIdx.y;
    const int tih  = blockIdx.x >> 3;   // tile-PAIR index in i (0..3)
    const int tj   = blockIdx.x & 7;    // 32-px tile in j
    float* wlds = &lds[wv*1136];

    const float eps8 = epsv[b] * 0.125f;
    const float RT   = 0.70710678118654752f;

    const int  xc   = lane & 7;
    const int  q1   = (lane >> 3) & 3;
    const int  cq   = (lane >> 3) & 1;
    const bool isY1 = lane < 32;
    const int  pi   = (lane & 3)*4;
    const int  pj   = lane >> 2;
    const float aax = (xc == 0 ? RT : 1.0f) * eps8;

    const int ti0 = tih*2, ti1 = tih*2 + 1;

    // ================= issue ALL loads up front (both tiles) ===============
    const float* tb = isY1 ? YBT : CBTc;
    const float4 t0 = *(const float4*)(tb + xc*8);
    const float4 t1 = *(const float4*)(tb + xc*8 + 4);

    const int ngY0 = (ti0*4 + (wv & 1)*2 + (q1 >> 1))*32 + tj*4 + (wv >> 1)*2 + (q1 & 1);
    const int ngC0 = (ti0*2 + (wv & 1))*16 + (tj*2 + (wv >> 1));
    const float* rb0 = isY1 ? (rvy + ((size_t)b*1024 + ngY0)*64)
                            : ((cq ? rvcr : rvcb) + ((size_t)b*256 + ngC0)*64);
    const float4 va0 = *(const float4*)(rb0 + xc*8);
    const float4 va1 = *(const float4*)(rb0 + xc*8 + 4);

    const int ngY1 = (ti1*4 + (wv & 1)*2 + (q1 >> 1))*32 + tj*4 + (wv >> 1)*2 + (q1 & 1);
    const int ngC1 = (ti1*2 + (wv & 1))*16 + (tj*2 + (wv >> 1));
    const float* rb1 = isY1 ? (rvy + ((size_t)b*1024 + ngY1)*64)
                            : ((cq ? rvcr : rvcb) + ((size_t)b*256 + ngC1)*64);
    const float4 vb0 = *(const float4*)(rb1 + xc*8);
    const float4 vb1 = *(const float4*)(rb1 + xc*8 + 4);

    const size_t pb0 = (size_t)b*196608
                     + (size_t)(tj*32 + (wv >> 1)*16 + pj)*256
                     + (size_t)(ti0*32 + (wv & 1)*16 + pi);
    const size_t pb1 = pb0 + 32;        // ti0 -> ti1 is +32 in i
    const float4 rP0 = *(const float4*)(pix + pb0);
    const float4 gP0 = *(const float4*)(pix + pb0 + 65536);
    const float4 bP0 = *(const float4*)(pix + pb0 + 131072);
    const float4 rP1 = *(const float4*)(pix + pb1);
    const float4 gP1 = *(const float4*)(pix + pb1 + 65536);
    const float4 bP1 = *(const float4*)(pix + pb1 + 131072);

    // ================= tile 0 then tile 1 (LDS slice reused) ===============
    process_tile(wlds, out, pb0, lane, aax, va0, va1, t0, t1, rP0, gP0, bP0);
    process_tile(wlds, out, pb1, lane, aax, vb0, vb1, t0, t1, rP1, gP1, bP1);
}

extern "C" void kernel_launch(void* const* d_in, const int* in_sizes, int n_in,
                              void* d_out, int out_size, void* d_ws, size_t ws_size,
                              hipStream_t stream) {
    const float* pix  = (const float*)d_in[0];
    const float* rvy  = (const float*)d_in[1];
    const float* rvcb = (const float*)d_in[2];
    const float* rvcr = (const float*)d_in[3];
    const float* eps  = (const float*)d_in[4];
    const int B = in_sizes[4];           // epsilon: one per batch
    dim3 grid(32, B);                    // 4x8 tile-pairs (2x 16x16 per wave)
    jpeg_kernel<<<grid, 256, 0, stream>>>(pix, rvy, rvcb, rvcr, eps, (float*)d_out);
}

// Round 8
// 24.428 us; speedup vs baseline: 1.0702x; 1.0702x over previous
//
#include <hip/hip_runtime.h>

// JPEG differentiable codec, fused. Identity: IDCT(DCT(p)+nf) = p + IDCT(nf);
// only the quantization NOISE is IDCT'd: nf = 0.125*eps*table*AA*rv.
// FINAL (= round-3 structure, best measured 24.6 us): 32x32-px tile / 256
// threads / 4 px per thread (low VGPR), fast 8-pt IDCT butterflies (literal
// constants) in both stages, rv read straight from global, loads ordered
// rv->tables->pixels so stage-1 overlaps pixel latency. Wave-aligned stage
// split: waves 0-1 Y, wave 2 chroma. 2 barriers.
// LDS per-octet bank model: stride-68 stage buffers, stride-36 nylds,
// stride-20 pool -> all accesses <=2-way.
//
// Session conclusion: six structural variants (block-sync / barrier-free /
// deep-tile / 2x-MLP) all plateau at 24.6-26 us. Logical traffic 129 MB
// (79 R + 49 W, algorithmically minimal) at the ~5.3 TB/s effective
// mixed-stream rate + graph-replay overhead ==> ~24-25 us wall. This kernel
// sits on it.
//
// Index map (validated rounds 0-6): img[b,i,j,c] = pixel_inp[b,c,j,i];
// Y block n = (i/8)*32 + j/8, in-block (x,y) = (i%8, j%8); ref tables are .T
// so effective table[x][y] = std[y][x]; chroma at (ci,cj)=(i/2,j/2),
// n_c = (ci/8)*16 + cj/8.

__constant__ float YBT[64] = {   // YBT[x*8+y] = std_luma[y][x]
  16,12,14,14,18,24,49,72,
  11,12,13,17,22,35,64,92,
  10,14,16,22,37,55,78,95,
  16,19,24,29,56,64,87,98,
  24,26,40,51,68,81,103,112,
  40,58,57,87,109,104,121,100,
  51,60,69,80,103,113,120,103,
  61,55,56,62,77,92,101,99};

__constant__ float CBTc[64] = {  // symmetric -> transpose = itself
  17,18,24,47,99,99,99,99,
  18,21,26,66,99,99,99,99,
  24,26,56,99,99,99,99,99,
  47,66,99,99,99,99,99,99,
  99,99,99,99,99,99,99,99,
  99,99,99,99,99,99,99,99,
  99,99,99,99,99,99,99,99,
  99,99,99,99,99,99,99,99};

// o[u] = sum_k t[k] * cos((2u+1)*k*pi/16)   (alpha folded upstream)
__device__ __forceinline__ void idct8(const float* __restrict__ t,
                                      float* __restrict__ o) {
    const float r  = 0.70710678118654752f;
    const float a  = 0.92387953251128674f;
    const float bq = 0.38268343236508977f;
    const float c1 = 0.98078528040323044f;
    const float c3 = 0.83146961230254524f;
    const float c5 = 0.55557023301960222f;
    const float c7 = 0.19509032201612827f;
    const float p  = fmaf(r,  t[4], t[0]);
    const float m  = fmaf(-r, t[4], t[0]);
    const float q  = fmaf(a,  t[2],  bq*t[6]);
    const float s  = fmaf(bq, t[2],  -a*t[6]);
    const float E0 = p + q, E3 = p - q, E1 = m + s, E2 = m - s;
    const float O0 = fmaf(c1,t[1], fmaf( c3,t[3], fmaf( c5,t[5],  c7*t[7])));
    const float O1 = fmaf(c3,t[1], fmaf(-c7,t[3], fmaf(-c1,t[5], -c5*t[7])));
    const float O2 = fmaf(c5,t[1], fmaf(-c1,t[3], fmaf( c7,t[5],  c3*t[7])));
    const float O3 = fmaf(c7,t[1], fmaf(-c5,t[3], fmaf( c3,t[5], -c1*t[7])));
    o[0]=E0+O0; o[7]=E0-O0; o[1]=E1+O1; o[6]=E1-O1;
    o[2]=E2+O2; o[5]=E2-O2; o[3]=E3+O3; o[4]=E3-O3;
}

__global__ __launch_bounds__(256) void jpeg_kernel(
    const float* __restrict__ pix,   // [B,3,256,256]
    const float* __restrict__ rvy,   // [B,1024,8,8]
    const float* __restrict__ rvcb,  // [B,256,8,8]
    const float* __restrict__ rvcr,  // [B,256,8,8]
    const float* __restrict__ epsv,  // [B]
    float* __restrict__ out)         // [B,3,256,256]
{
    __shared__ float sY[16*68];      // stage-1 Y: [nl][x][v], block stride 68
    __shared__ float sC[8*68];       // 4 Cb + 4 Cr
    __shared__ float nylds[32*36];   // Y noise [j][i], row stride 36
    __shared__ float pool[2*320];    // centered pooled chroma [ch][cj][ci], cj stride 20

    const int tid = threadIdx.x;
    const int qi  = tid & 7;           // i-quad (4 px)
    const int dj  = tid >> 3;          // row 0..31
    const int b   = blockIdx.y;
    const int ti  = blockIdx.x >> 3;   // 32-px tile in i
    const int tj  = blockIdx.x & 7;    // 32-px tile in j

    const float eps8 = epsv[b] * 0.125f;   // 0.25(idct)*0.5(noisy_round)
    const float RT   = 0.70710678118654752f;

    // ---- issue stage-1 loads FIRST (rv + table), pixels second, so the
    //      stage-1 idct only waits on the early vmem ops ----
    float4 v0, v1, t0, t1;
    int nl = 0;
    const int xc = tid & 7;
    const bool isY = tid < 128, isC = (tid >= 128) && (tid < 192);
    if (isY) {
        nl = tid >> 3;                               // 0..15
        const int bx = nl >> 2, by = nl & 3;
        const int ng = (ti*4 + bx)*32 + (tj*4 + by);
        const float* rp = rvy + ((size_t)b*1024 + ng)*64 + xc*8;
        v0 = *(const float4*)rp;
        v1 = *(const float4*)(rp + 4);
        t0 = *(const float4*)&YBT[xc*8];
        t1 = *(const float4*)&YBT[xc*8 + 4];
    } else if (isC) {
        nl = (tid - 128) >> 3;                       // 0..7; ch = nl>>2
        const int ch = nl >> 2, idx = nl & 3, cbx = idx >> 1, cby = idx & 1;
        const int ng = (ti*2 + cbx)*16 + (tj*2 + cby);
        const float* __restrict__ rvc = ch ? rvcr : rvcb;
        const float* rp = rvc + ((size_t)b*256 + ng)*64 + xc*8;
        v0 = *(const float4*)rp;
        v1 = *(const float4*)(rp + 4);
        t0 = *(const float4*)&CBTc[xc*8];
        t1 = *(const float4*)&CBTc[xc*8 + 4];
    }

    const int i0 = ti*32 + qi*4;
    const int j  = tj*32 + dj;
    const size_t pb = (size_t)b*196608 + (size_t)j*256 + i0;
    const float4 rP = *(const float4*)(pix + pb);
    const float4 gP = *(const float4*)(pix + pb + 65536);
    const float4 bP = *(const float4*)(pix + pb + 131072);

    // ---- stage 1: column IDCT of scaled noise (waves 0-2) ----
    if (isY || isC) {
        const float aax = (xc == 0 ? RT : 1.0f) * eps8;
        float t[8];
        t[0] = v0.x * (t0.x * aax * RT);   // alpha_y on y=0
        t[1] = v0.y * (t0.y * aax);
        t[2] = v0.z * (t0.z * aax);
        t[3] = v0.w * (t0.w * aax);
        t[4] = v1.x * (t1.x * aax);
        t[5] = v1.y * (t1.y * aax);
        t[6] = v1.z * (t1.z * aax);
        t[7] = v1.w * (t1.w * aax);
        float o[8];
        idct8(t, o);
        float* ws = (isY ? sY : sC) + nl*68 + xc*8;
        *(float4*)ws       = make_float4(o[0], o[1], o[2], o[3]);
        *(float4*)(ws + 4) = make_float4(o[4], o[5], o[6], o[7]);
    }

    // ---- YCC + chroma 2x2 pool (all threads; pixels have arrived) ----
    const float rr[4] = {rP.x, rP.y, rP.z, rP.w};
    const float gg[4] = {gP.x, gP.y, gP.z, gP.w};
    const float bb[4] = {bP.x, bP.y, bP.z, bP.w};
    float yv[4], cbv[4], crv[4];
    #pragma unroll
    for (int c = 0; c < 4; ++c) {
        yv[c]  = fmaf(0.299f, rr[c], fmaf(0.587f, gg[c], 0.114f*bb[c]));
        cbv[c] = fmaf(-0.168736f, rr[c], fmaf(-0.331264f, gg[c], 0.5f*bb[c]));
        crv[c] = fmaf(0.5f, rr[c], fmaf(-0.418688f, gg[c], -0.081312f*bb[c]));
    }
    float cb01 = cbv[0] + cbv[1], cb23 = cbv[2] + cbv[3];
    float cr01 = crv[0] + crv[1], cr23 = crv[2] + crv[3];
    cb01 += __shfl_xor(cb01, 8);   // partner row j^1 (dj bit0 = lane bit3)
    cb23 += __shfl_xor(cb23, 8);
    cr01 += __shfl_xor(cr01, 8);
    cr23 += __shfl_xor(cr23, 8);
    if ((dj & 1) == 0) {           // centered pooled chroma (no +128)
        float* pp = &pool[(dj >> 1)*20 + qi*2];
        *(float2*)pp         = make_float2(0.25f*cb01, 0.25f*cb23);
        *(float2*)(pp + 320) = make_float2(0.25f*cr01, 0.25f*cr23);
    }
    __syncthreads();   // A: sY/sC/pool ready

    // ---- stage 2: row IDCT ----
    if (tid < 128) {               // Y rows -> nylds
        const int n2 = tid >> 3, v2 = tid & 7;
        const float* rs = &sY[n2*68 + v2];
        float t[8];
        #pragma unroll
        for (int x = 0; x < 8; ++x) t[x] = rs[x*8];
        float o[8];
        idct8(t, o);
        const int jj = (n2 & 3)*8 + v2;
        float* wn = &nylds[jj*36 + (n2 >> 2)*8];
        *(float4*)wn       = make_float4(o[0], o[1], o[2], o[3]);
        *(float4*)(wn + 4) = make_float4(o[4], o[5], o[6], o[7]);
    } else if (tid < 192) {        // chroma rows -> add into pool
        const int c2 = tid - 128;
        const int nc2 = c2 >> 3, vc2 = c2 & 7;
        const float* rs = &sC[nc2*68 + vc2];
        float t[8];
        #pragma unroll
        for (int x = 0; x < 8; ++x) t[x] = rs[x*8];
        float o[8];
        idct8(t, o);
        const int ch = nc2 >> 2, idx = nc2 & 3, cbx = idx >> 1, cby = idx & 1;
        float* pp = &pool[ch*320 + (cby*8 + vc2)*20 + cbx*8];
        const float4 p0 = *(const float4*)pp;
        const float4 p1 = *(const float4*)(pp + 4);
        *(float4*)pp       = make_float4(p0.x+o[0], p0.y+o[1], p0.z+o[2], p0.w+o[3]);
        *(float4*)(pp + 4) = make_float4(p1.x+o[4], p1.y+o[5], p1.z+o[6], p1.w+o[7]);
    }
    __syncthreads();   // B: nylds + chroma-final pool ready

    // ---- final: recombine, YCC->RGB, clip, store ----
    const float4 yn4 = *(const float4*)&nylds[dj*36 + qi*4];
    const int cj = dj >> 1;
    const float2 cbp = *(const float2*)&pool[cj*20 + qi*2];
    const float2 crp = *(const float2*)&pool[320 + cj*20 + qi*2];
    const float yn[4]  = {yn4.x, yn4.y, yn4.z, yn4.w};
    const float cbf[4] = {cbp.x, cbp.x, cbp.y, cbp.y};
    const float crf[4] = {crp.x, crp.x, crp.y, crp.y};
    float ro[4], go[4], bo[4];
    #pragma unroll
    for (int c = 0; c < 4; ++c) {
        const float yf = yv[c] + yn[c];
        float r_ = fmaf(1.402f, crf[c], yf);
        float g_ = fmaf(-0.344136f, cbf[c], fmaf(-0.714136f, crf[c], yf));
        float b_ = fmaf(1.772f, cbf[c], yf);
        ro[c] = fminf(fmaxf(r_, 0.0f), 255.0f);
        go[c] = fminf(fmaxf(g_, 0.0f), 255.0f);
        bo[c] = fminf(fmaxf(b_, 0.0f), 255.0f);
    }
    *(float4*)(out + pb)          = make_float4(ro[0], ro[1], ro[2], ro[3]);
    *(float4*)(out + pb + 65536)  = make_float4(go[0], go[1], go[2], go[3]);
    *(float4*)(out + pb + 131072) = make_float4(bo[0], bo[1], bo[2], bo[3]);
}

extern "C" void kernel_launch(void* const* d_in, const int* in_sizes, int n_in,
                              void* d_out, int out_size, void* d_ws, size_t ws_size,
                              hipStream_t stream) {
    const float* pix  = (const float*)d_in[0];
    const float* rvy  = (const float*)d_in[1];
    const float* rvcb = (const float*)d_in[2];
    const float* rvcr = (const float*)d_in[3];
    const float* eps  = (const float*)d_in[4];
    const int B = in_sizes[4];           // epsilon: one per batch
    dim3 grid(64, B);                    // 8x8 tiles of 32x32 px, per batch
    jpeg_kernel<<<grid, 256, 0, stream>>>(pix, rvy, rvcb, rvcr, eps, (float*)d_out);
}